// Round 5
// baseline (509.715 us; speedup 1.0000x reference)
//
#include <hip/hip_runtime.h>
#include <math.h>

#define NB 16
#define LTOT 327
#define SDIM 256
#define ZD 64
#define NZ (NB * LTOT)
#define TSTRIDE 68     // 64 + 4 pad, keeps 16B alignment
#define GRID 2048      // 256 CU x 8 blocks: fill-like persistent shape

typedef float nt4 __attribute__((ext_vector_type(4)));   // native vec for nontemporal builtins

// region starts (l-space; l=0 collapse token) and lengths
__device__ __constant__ int d_starts[7] = {1, 25, 41, 89, 193, 209, 313};
__device__ __constant__ int d_lens[7]   = {24, 16, 48, 104, 16, 104, 14};

// j-segment boundaries: [token][cdr3][pep][mhc][hv][hj][lv][lj]
__device__ __constant__ int seg_s[8] = {0, 1, 25, 41, 89, 193, 209, 313};
__device__ __constant__ int seg_e[8] = {1, 25, 41, 89, 193, 209, 313, 327};

__device__ __forceinline__ int regid(int x) {
    return (x >= 1) + (x >= 25) + (x >= 41) + (x >= 89) + (x >= 193) + (x >= 209) + (x >= 313);
}

__device__ __forceinline__ int pair_id(int i, int j, int ri, int rj) {
    if ((i == 0) && (j == 0)) return 0;
    if ((i == 0) || (j == 0)) return 1;
    if ((ri == 1) && (rj == 1)) {
        int d = i > j ? i - j : j - i;
        if (d == 1) return 2;
        if (d != 0) return 3;
        return 0;                 // cdr3 diagonal stays 0 (matches jnp.where order)
    }
    if ((ri == 1) || (rj == 1)) return 4;
    if (ri == rj) return 5 + ri - 2;
    int a = (ri < rj ? ri : rj) - 2;
    int c = (ri < rj ? rj : ri) - 2;
    return 11 + a * (11 - a) / 2 + (c - a - 1);   // N_COND=6
}

// -------- persistent fused kernel --------
// GRID blocks, each grid-strides over 2*NZ work units.
// Units [0, NZ): z-rows (one (b,i) row of (327,64), streaming NT stores).
// Units [NZ, 2*NZ): s-rows (one (b,l) row of (256,)).
// The 32-entry pair table is built ONCE per block; waves stay long-lived so the
// store pipe remains continuously full (fill-kernel shape).
__global__ __launch_bounds__(256) void fused_persist(
    const float* __restrict__ p1W, const float* __restrict__ p1b,
    const float* __restrict__ p2W, const float* __restrict__ p2b,
    const float* __restrict__ s0, const float* __restrict__ s1,
    const float* __restrict__ s2, const float* __restrict__ s3,
    const float* __restrict__ s4, const float* __restrict__ s5,
    const float* __restrict__ s6,
    const float* __restrict__ seqW, const float* __restrict__ seqb,
    const float* __restrict__ posW, const float* __restrict__ posb,
    const float* __restrict__ ctok, const float* __restrict__ cw,
    const float* __restrict__ rw,
    float* __restrict__ out, float* __restrict__ outz)
{
    __shared__ __align__(16) float table[32 * TSTRIDE];  // persists across units
    __shared__ float sh_seq[21];
    __shared__ float sh_pe[64];
    int t = threadIdx.x;

    // build pair table once per block
    for (int idx = t; idx < 32 * 64; idx += 256) {
        int p = idx >> 6, c = idx & 63;
        float v;
        if (c < 32) v = p1W[c * 8 + (p >> 2)] + p1b[c];
        else        v = p2W[(c - 32) * 4 + (p & 3)] + p2b[c - 32];
        table[p * TSTRIDE + c] = v;
    }
    __syncthreads();

    int c4 = t & 15;           // which float4 of the 16 in a 64-float row
    int jo = t >> 4;           // j offset within a 16-row stripe

    for (int u = blockIdx.x; u < 2 * NZ; u += GRID) {
        if (u < NZ) {
            // ---------------- z unit: one (b,i) row, pure streaming stores
            int i = u % LTOT;
            int ri = regid(i);
            // one wave store-instruction = 4 consecutive 256B rows = 1KB contiguous
            nt4* dst = (nt4*)(outz + (size_t)u * (LTOT * ZD));

            #pragma unroll
            for (int s = 0; s < 8; s++) {
                int js = seg_s[s], je = seg_e[s];
                if (ri == 1 && s == 1) {
                    // cdr3 row x cdr3 segment: p varies with |i-j| in {0,2(adj),3}
                    nt4 v0 = *(const nt4*)(table + 0 * TSTRIDE + c4 * 4);
                    nt4 v2 = *(const nt4*)(table + 2 * TSTRIDE + c4 * 4);
                    nt4 v3 = *(const nt4*)(table + 3 * TSTRIDE + c4 * 4);
                    for (int j = js + jo; j < je; j += 16) {
                        int d = i > j ? i - j : j - i;
                        nt4 v = (d == 0) ? v0 : ((d == 1) ? v2 : v3);
                        __builtin_nontemporal_store(v, dst + j * 16 + c4);
                    }
                } else {
                    int p = pair_id(i, js, ri, regid(js));   // uniform over the segment
                    nt4 v = *(const nt4*)(table + p * TSTRIDE + c4 * 4);
                    for (int j = js + jo; j < je; j += 16) {
                        __builtin_nontemporal_store(v, dst + j * 16 + c4);
                    }
                }
            }
        } else {
            // ---------------- s unit: one (b,l) row of (256,)
            int sb = u - NZ;       // b*LTOT + l
            int l = sb % LTOT;
            int b = sb / LTOT;
            int e = t;

            if (l == 0) {
                out[(size_t)sb * SDIM + e] = cw[0] * ctok[e];
            } else {
                int k = (l >= 25) + (l >= 41) + (l >= 89) + (l >= 193) + (l >= 209) + (l >= 313);
                int pl = l - d_starts[k];
                const float* sp;
                switch (k) {
                    case 0: sp = s0; break; case 1: sp = s1; break; case 2: sp = s2; break;
                    case 3: sp = s3; break; case 4: sp = s4; break; case 5: sp = s5; break;
                    default: sp = s6;
                }
                __syncthreads();   // previous unit's sh_* readers are done
                if (e < 21) sh_seq[e] = sp[((size_t)b * d_lens[k] + pl) * 21 + e];
                if (e < 64) {
                    float scale = exp2f(-(float)e * (13.287712379549449f / 64.0f)); // 10000^(-e/64)
                    float ang = (float)pl * scale;
                    sh_pe[e] = (e & 1) ? cosf(ang) : sinf(ang);
                }
                __syncthreads();

                float se = seqb[e];
                const float* wrow = seqW + e * 21;
                #pragma unroll
                for (int d = 0; d < 21; d++) se = fmaf(sh_seq[d], wrow[d], se);

                float pe = posb[e];
                const float* pwrow = posW + e * 64;
                #pragma unroll 8
                for (int i2 = 0; i2 < 64; i2++) pe = fmaf(sh_pe[i2], pwrow[i2], pe);

                out[(size_t)sb * SDIM + e] = rw[2 * k] * se + rw[2 * k + 1] * pe;
            }
        }
    }
}

extern "C" void kernel_launch(void* const* d_in, const int* in_sizes, int n_in,
                              void* d_out, int out_size, void* d_ws, size_t ws_size,
                              hipStream_t stream) {
    const float* seq0 = (const float*)d_in[0];
    const float* seq1 = (const float*)d_in[1];
    const float* seq2 = (const float*)d_in[2];
    const float* seq3 = (const float*)d_in[3];
    const float* seq4 = (const float*)d_in[4];
    const float* seq5 = (const float*)d_in[5];
    const float* seq6 = (const float*)d_in[6];
    const float* seqW = (const float*)d_in[7];
    const float* seqb = (const float*)d_in[8];
    const float* posW = (const float*)d_in[9];
    const float* posb = (const float*)d_in[10];
    const float* p1W  = (const float*)d_in[11];
    const float* p1b  = (const float*)d_in[12];
    const float* p2W  = (const float*)d_in[13];
    const float* p2b  = (const float*)d_in[14];
    const float* ctok = (const float*)d_in[15];
    const float* cw   = (const float*)d_in[16];
    const float* rw   = (const float*)d_in[17];

    float* out = (float*)d_out;
    float* outz = out + (size_t)NB * LTOT * SDIM;

    // single persistent launch: z units flood first, s units drain last
    fused_persist<<<GRID, 256, 0, stream>>>(p1W, p1b, p2W, p2b,
                                            seq0, seq1, seq2, seq3, seq4, seq5, seq6,
                                            seqW, seqb, posW, posb, ctok, cw, rw,
                                            out, outz);
}